// Round 11
// baseline (1462.143 us; speedup 1.0000x reference)
//
#include <hip/hip_runtime.h>
#include <math.h>

#define T_STEPS 24
#define F_IN 10
#define HDIM 128
#define E_EDGES 80000
#define B_BATCH 8
#define N_NODES 5000
#define BN_TOTAL 40000
#define BE 640000
#define NE 680000

typedef __attribute__((ext_vector_type(8))) short s16x8;
typedef __attribute__((ext_vector_type(4))) short s16x4;
typedef __attribute__((ext_vector_type(4))) float fx4;
typedef __attribute__((ext_vector_type(2))) float fx2;
typedef __attribute__((ext_vector_type(4))) unsigned int ux4;
typedef __attribute__((ext_vector_type(2))) unsigned int ux2;

__device__ __forceinline__ float rcpf_(float v) { return __builtin_amdgcn_rcpf(v); }
__device__ __forceinline__ float sigmoidf_(float v) { return rcpf_(1.f + __expf(-v)); }
__device__ __forceinline__ float tanhf_(float v) { float e = __expf(2.f * v); return 1.f - 2.f * rcpf_(e + 1.f); }

__device__ __forceinline__ short f2b(float f) {
    unsigned u = __float_as_uint(f);
    unsigned r = (u + 0x7fffu + ((u >> 16) & 1u)) >> 16;
    return (short)r;
}
__device__ __forceinline__ unsigned int pkbf(float a, float b) {
    unsigned int r;
    asm("v_cvt_pk_bf16_f32 %0, %1, %2" : "=v"(r) : "v"(a), "v"(b));
    return r;
}
__device__ __forceinline__ float bfu(unsigned short u) {
    return __uint_as_float(((unsigned)u) << 16);
}

// ---------------- pack weights into MFMA A-fragment order (bf16), nf-major ----------------
// shorts: [0,49152) hh0 ; [49152,98304) hh1 ; [98304,147456) ih1 ; [147456,159744) ih0(K pad 10->32)
//         [159744,225280) g1w ; [225280,290816) g2w
__global__ void pack_w(const float* __restrict__ wih0, const float* __restrict__ whh0,
                       const float* __restrict__ wih1, const float* __restrict__ whh1,
                       const float* __restrict__ g1w, const float* __restrict__ g2w,
                       short* __restrict__ pk) {
    int id = blockIdx.x * 256 + threadIdx.x;
    if (id >= 290816) return;
    if (id < 147456) {
        int mat = id / 49152, r = id % 49152;
        int nf = r / 2048, r2 = r % 2048, kf = r2 / 512, r3 = r2 % 512, lane = r3 / 8, j = r3 % 8;
        int n = nf * 16 + (lane & 15), k = kf * 32 + (lane >> 4) * 8 + j;
        const float* src = (mat == 0) ? whh0 : (mat == 1) ? whh1 : wih1;
        pk[id] = f2b(src[n * 128 + k]);
    } else if (id < 159744) {
        int r = id - 147456;
        int nf = r / 512, r2 = r % 512, lane = r2 / 8, j = r2 % 8;
        int n = nf * 16 + (lane & 15), k = (lane >> 4) * 8 + j;
        pk[id] = (k < F_IN) ? f2b(wih0[n * F_IN + k]) : (short)0;
    } else {
        const float* src = (id < 225280) ? g1w : g2w;
        int r = (id < 225280) ? (id - 159744) : (id - 225280);
        int nf = r / 2048, r2 = r % 2048, kf = r2 / 512, r3 = r2 % 512, lane = r3 / 8, j = r3 % 8;
        int n = nf * 16 + (lane & 15), k = kf * 32 + (lane >> 4) * 8 + j;
        pk[id] = f2b(src[n * 128 + k]);
    }
}

// ------------- fused 2-layer GRU; 32 seqs/block, weights streamed from L2 -------------
// 8 waves; wave w owns cols [w*16,(w+1)*16) x 32 seqs. acc 32 regs; target <=128 VGPR
// -> 4 waves/SIMD (2 blocks/CU) for cross-block phase overlap.
__global__ __launch_bounds__(512, 4) void gru_mfma(
    const float* __restrict__ x, const short* __restrict__ pk,
    const float* __restrict__ bih0, const float* __restrict__ bhh0,
    const float* __restrict__ bih1, const float* __restrict__ bhh1,
    float* __restrict__ temporal) {
    __shared__ __align__(16) short h1b[32 * 128];     // 8 KB
    __shared__ __align__(16) short h2b[32 * 128];     // 8 KB
    __shared__ __align__(16) float blds[2][4][128];   // 4 KB
    const int tid = threadIdx.x;
    const int w = tid >> 6, l = tid & 63;
    const int lm = l & 15, lk = l >> 4;
    const int jb = w * 16 + lk * 4;
    const long sb = (long)blockIdx.x * 32;   // 1250*32 == 40000

    if (tid < 128) {
        const int j = tid;
        blds[0][0][j] = bih0[j] + bhh0[j];
        blds[0][1][j] = bih0[128 + j] + bhh0[128 + j];
        blds[0][2][j] = bhh0[256 + j];
        blds[0][3][j] = bih0[256 + j];
    } else if (tid < 256) {
        const int j = tid - 128;
        blds[1][0][j] = bih1[j] + bhh1[j];
        blds[1][1][j] = bih1[128 + j] + bhh1[128 + j];
        blds[1][2][j] = bhh1[256 + j];
        blds[1][3][j] = bih1[256 + j];
    }
    for (int i = tid; i < 32 * 128; i += 512) { h1b[i] = 0; h2b[i] = 0; }

    fx4 h1s[2], h2s[2];
#pragma unroll
    for (int mf = 0; mf < 2; ++mf) { h1s[mf] = (fx4)(0.f); h2s[mf] = (fx4)(0.f); }

    __syncthreads();

    for (int tt = 0; tt < T_STEPS; ++tt) {
        // ---- x loads, converted to bf16 immediately ----
        ux4 xu[2];
#pragma unroll
        for (int mf = 0; mf < 2; ++mf) {
            fx2 a0 = (fx2)(0.f), a1 = (fx2)(0.f), a2 = (fx2)(0.f), a3 = (fx2)(0.f);
            const float* xr = x + (sb + mf * 16 + lm) * (T_STEPS * F_IN) + tt * F_IN;
            if (lk == 0) {
                a0 = *(const fx2*)(xr);     a1 = *(const fx2*)(xr + 2);
                a2 = *(const fx2*)(xr + 4); a3 = *(const fx2*)(xr + 6);
            } else if (lk == 1) {
                a0 = *(const fx2*)(xr + 8);
            }
            ux4 t = { pkbf(a0.x, a0.y), pkbf(a1.x, a1.y), pkbf(a2.x, a2.y), pkbf(a3.x, a3.y) };
            xu[mf] = t;
        }
        fx4 acc[4][2];
#pragma unroll
        for (int p = 0; p < 4; ++p) {
            const fx4 bv = *(const fx4*)&blds[0][p][jb];
            acc[p][0] = bv; acc[p][1] = bv;
        }
        // ===== layer 0: hh0 (A from L2, B = h1 old), parts r,z,nh =====
#pragma unroll
        for (int kf = 0; kf < 4; ++kf) {
            s16x8 bfr[2];
#pragma unroll
            for (int mf = 0; mf < 2; ++mf) {
                const int m = mf * 16 + lm;
                const int slot = (kf * 4 + lk) ^ (m & 7);
                bfr[mf] = *(const s16x8*)&h1b[m * 128 + slot * 8];
            }
#pragma unroll
            for (int g = 0; g < 3; ++g) {
                const int part = (g == 2) ? 2 : g;
                const s16x8 af = *(const s16x8*)&pk[((((g * 8 + w) * 4) + kf) * 64 + l) * 8];
#pragma unroll
                for (int mf = 0; mf < 2; ++mf)
                    acc[part][mf] = __builtin_amdgcn_mfma_f32_16x16x32_bf16(af, bfr[mf], acc[part][mf], 0, 0, 0);
            }
        }
        // ---- ih0 (A from L2, B = x frags), parts r,z,ni ----
#pragma unroll
        for (int g = 0; g < 3; ++g) {
            const int part = (g == 2) ? 3 : g;
            const s16x8 af = *(const s16x8*)&pk[147456 + ((g * 8 + w) * 64 + l) * 8];
#pragma unroll
            for (int mf = 0; mf < 2; ++mf)
                acc[part][mf] = __builtin_amdgcn_mfma_f32_16x16x32_bf16(af, __builtin_bit_cast(s16x8, xu[mf]), acc[part][mf], 0, 0, 0);
        }
        // ---- elementwise layer 0 -> h1 ----
        ux2 w1[2];
#pragma unroll
        for (int mf = 0; mf < 2; ++mf) {
#pragma unroll
            for (int rg = 0; rg < 4; ++rg) {
                const float r = sigmoidf_(acc[0][mf][rg]);
                const float z = sigmoidf_(acc[1][mf][rg]);
                const float n = tanhf_(acc[3][mf][rg] + r * acc[2][mf][rg]);
                h1s[mf][rg] = n + z * (h1s[mf][rg] - n);
            }
            ux2 q = { pkbf(h1s[mf][0], h1s[mf][1]), pkbf(h1s[mf][2], h1s[mf][3]) };
            w1[mf] = q;
        }
        // ===== layer 1: hh1 (A from L2, B = h2 old), parts r,z,nh =====
#pragma unroll
        for (int p = 0; p < 4; ++p) {
            const fx4 bv = *(const fx4*)&blds[1][p][jb];
            acc[p][0] = bv; acc[p][1] = bv;
        }
#pragma unroll
        for (int kf = 0; kf < 4; ++kf) {
            s16x8 bfr[2];
#pragma unroll
            for (int mf = 0; mf < 2; ++mf) {
                const int m = mf * 16 + lm;
                const int slot = (kf * 4 + lk) ^ (m & 7);
                bfr[mf] = *(const s16x8*)&h2b[m * 128 + slot * 8];
            }
#pragma unroll
            for (int g = 0; g < 3; ++g) {
                const int part = (g == 2) ? 2 : g;
                const s16x8 af = *(const s16x8*)&pk[49152 + ((((g * 8 + w) * 4) + kf) * 64 + l) * 8];
#pragma unroll
                for (int mf = 0; mf < 2; ++mf)
                    acc[part][mf] = __builtin_amdgcn_mfma_f32_16x16x32_bf16(af, bfr[mf], acc[part][mf], 0, 0, 0);
            }
        }
        __syncthreads();   // all reads of h1b(old)/h2b(old) complete
#pragma unroll
        for (int mf = 0; mf < 2; ++mf) {
            const int m = mf * 16 + lm;
            const int slot = (jb >> 3) ^ (m & 7);
            *(ux2*)&h1b[m * 128 + slot * 8 + (jb & 7)] = w1[mf];
        }
        __syncthreads();   // h1 new visible
        // ===== layer 1: ih1 (A from L2, B = h1 new), parts r,z,ni =====
#pragma unroll
        for (int kf = 0; kf < 4; ++kf) {
            s16x8 bfr[2];
#pragma unroll
            for (int mf = 0; mf < 2; ++mf) {
                const int m = mf * 16 + lm;
                const int slot = (kf * 4 + lk) ^ (m & 7);
                bfr[mf] = *(const s16x8*)&h1b[m * 128 + slot * 8];
            }
#pragma unroll
            for (int g = 0; g < 3; ++g) {
                const int part = (g == 2) ? 3 : g;
                const s16x8 af = *(const s16x8*)&pk[98304 + ((((g * 8 + w) * 4) + kf) * 64 + l) * 8];
#pragma unroll
                for (int mf = 0; mf < 2; ++mf)
                    acc[part][mf] = __builtin_amdgcn_mfma_f32_16x16x32_bf16(af, bfr[mf], acc[part][mf], 0, 0, 0);
            }
        }
        // ---- elementwise layer 1 -> h2, publish ----
#pragma unroll
        for (int mf = 0; mf < 2; ++mf) {
#pragma unroll
            for (int rg = 0; rg < 4; ++rg) {
                const float r = sigmoidf_(acc[0][mf][rg]);
                const float z = sigmoidf_(acc[1][mf][rg]);
                const float n = tanhf_(acc[3][mf][rg] + r * acc[2][mf][rg]);
                h2s[mf][rg] = n + z * (h2s[mf][rg] - n);
            }
            const int m = mf * 16 + lm;
            const int slot = (jb >> 3) ^ (m & 7);
            ux2 q = { pkbf(h2s[mf][0], h2s[mf][1]), pkbf(h2s[mf][2], h2s[mf][3]) };
            *(ux2*)&h2b[m * 128 + slot * 8 + (jb & 7)] = q;
        }
        __syncthreads();   // h2 new visible for next step
    }
#pragma unroll
    for (int mf = 0; mf < 2; ++mf) {
        const long m = sb + mf * 16 + lm;
        *(fx4*)&temporal[m * 128 + jb] = h2s[mf];
    }
}

// ---------------- CSR build ----------------
__global__ void csr_count(const int* __restrict__ edge1, int* __restrict__ cnt) {
    int e = blockIdx.x * 256 + threadIdx.x;
    if (e >= NE) return;
    int d;
    if (e < BE) { int b = e / E_EDGES; d = edge1[e - b * E_EDGES] + b * N_NODES; }
    else d = e - BE;
    atomicAdd(&cnt[d], 1);
}

__global__ void csr_scan(const int* cnt, int* offs, int* curs) {
    __shared__ int part[1024];
    const int t = threadIdx.x;
    const int base = t * 40;
    int end = base + 40; if (end > BN_TOTAL) end = BN_TOTAL;
    int s = 0;
    for (int i = base; i < end; ++i) s += cnt[i];
    part[t] = s;
    __syncthreads();
    for (int off = 1; off < 1024; off <<= 1) {
        int v = (t >= off) ? part[t - off] : 0;
        __syncthreads();
        part[t] += v;
        __syncthreads();
    }
    int run = part[t] - s;
    for (int i = base; i < end; ++i) {
        int c = cnt[i];
        offs[i] = run; curs[i] = run; run += c;
    }
    if (t == 1023) offs[BN_TOTAL] = NE;
}

__global__ void csr_fill(const int* __restrict__ edge1, int* __restrict__ curs, int* __restrict__ esort) {
    int e = blockIdx.x * 256 + threadIdx.x;
    if (e >= NE) return;
    int d;
    if (e < BE) { int b = e / E_EDGES; d = edge1[e - b * E_EDGES] + b * N_NODES; }
    else d = e - BE;
    int pos = atomicAdd(&curs[d], 1);
    esort[pos] = e;
}

// ------- GAT: wh = feat @ W.T via MFMA (128 rows x one head per block), bf16 out -------
__global__ __launch_bounds__(256, 2) void gat_gemm(const float* __restrict__ feat,
                                                   const short* __restrict__ pkg,
                                                   const float* __restrict__ asrc,
                                                   const float* __restrict__ adst,
                                                   unsigned short* __restrict__ whb,
                                                   float* __restrict__ AS, float* __restrict__ AD) {
    __shared__ __align__(16) short fb[128 * 128];   // 32 KB bf16, XOR-swizzled
    __shared__ float reda[4][128];
    __shared__ float redb[4][128];
    const int tid = threadIdx.x;
    const int w = tid >> 6, l = tid & 63;
    const int lm = l & 15, lk = l >> 4;
    const int i0 = blockIdx.x * 128;
    const int j0 = blockIdx.y * 128;     // == head*128
#pragma unroll
    for (int it = 0; it < 16; ++it) {
        const int idx = it * 256 + tid;
        const int r = idx >> 5, kq = idx & 31;
        fx4 v = (fx4)(0.f);
        const int row = i0 + r;
        if (row < BN_TOTAL) v = *(const fx4*)&feat[(size_t)row * 128 + kq * 4];
        const int slot = (kq >> 1) ^ (r & 7);
        ux2 pv = { pkbf(v.x, v.y), pkbf(v.z, v.w) };
        *(ux2*)&fb[r * 128 + slot * 8 + (kq & 1) * 4] = pv;
    }
    __syncthreads();
    fx4 acc[2][8];
#pragma unroll
    for (int jf = 0; jf < 2; ++jf)
#pragma unroll
        for (int mf = 0; mf < 8; ++mf) acc[jf][mf] = (fx4)(0.f);
#pragma unroll
    for (int kf = 0; kf < 4; ++kf) {
        s16x8 bfr[8];
#pragma unroll
        for (int mf = 0; mf < 8; ++mf) {
            const int m = mf * 16 + lm;
            const int slot = (kf * 4 + lk) ^ (m & 7);
            bfr[mf] = *(const s16x8*)&fb[m * 128 + slot * 8];
        }
#pragma unroll
        for (int jf = 0; jf < 2; ++jf) {
            const int nf = (j0 >> 4) + w * 2 + jf;
            const s16x8 af = *(const s16x8*)&pkg[((nf * 4 + kf) * 64 + l) * 8];
#pragma unroll
            for (int mf = 0; mf < 8; ++mf)
                acc[jf][mf] = __builtin_amdgcn_mfma_f32_16x16x32_bf16(af, bfr[mf], acc[jf][mf], 0, 0, 0);
        }
    }
    // ---- write wh (bf16) + fused alpha partials (fp32) ----
    float ps[8], pd[8];
#pragma unroll
    for (int mf = 0; mf < 8; ++mf) { ps[mf] = 0.f; pd[mf] = 0.f; }
#pragma unroll
    for (int jf = 0; jf < 2; ++jf) {
        const int cb = w * 32 + jf * 16 + lk * 4;
        const fx4 s4 = *(const fx4*)&asrc[j0 + cb];
        const fx4 d4 = *(const fx4*)&adst[j0 + cb];
        const int nb = j0 + cb;
#pragma unroll
        for (int mf = 0; mf < 8; ++mf) {
            const int m = i0 + mf * 16 + lm;
            const fx4 a = acc[jf][mf];
            if (m < BN_TOTAL) {
                ux2 pv = { pkbf(a.x, a.y), pkbf(a.z, a.w) };
                *(ux2*)&whb[(size_t)m * 512 + nb] = pv;
            }
            ps[mf] += a.x * s4.x + a.y * s4.y + a.z * s4.z + a.w * s4.w;
            pd[mf] += a.x * d4.x + a.y * d4.y + a.z * d4.z + a.w * d4.w;
        }
    }
#pragma unroll
    for (int off = 16; off <= 32; off <<= 1) {
#pragma unroll
        for (int mf = 0; mf < 8; ++mf) {
            ps[mf] += __shfl_xor(ps[mf], off);
            pd[mf] += __shfl_xor(pd[mf], off);
        }
    }
    if (lk == 0) {
#pragma unroll
        for (int mf = 0; mf < 8; ++mf) {
            reda[w][mf * 16 + lm] = ps[mf];
            redb[w][mf * 16 + lm] = pd[mf];
        }
    }
    __syncthreads();
    if (tid < 128) {
        const int row = i0 + tid;
        if (row < BN_TOTAL) {
            const float a = reda[0][tid] + reda[1][tid] + reda[2][tid] + reda[3][tid];
            const float b = redb[0][tid] + redb[1][tid] + redb[2][tid] + redb[3][tid];
            AS[row * 4 + (j0 >> 7)] = a;
            AD[row * 4 + (j0 >> 7)] = b;
        }
    }
}

__device__ __forceinline__ int decode_src(int eid, const int* __restrict__ edge0) {
    if (eid < BE) { int b = eid / E_EDGES; return edge0[eid - b * E_EDGES] + b * N_NODES; }
    return eid - BE;
}

// ------- per-node softmax attention + aggregate; no-max exp (scores bounded) -------
__global__ __launch_bounds__(256) void gat_aggregate(const unsigned short* __restrict__ whb,
                                                     const float* __restrict__ AS, const float* __restrict__ AD,
                                                     const int* __restrict__ offs, const int* __restrict__ esort,
                                                     const int* __restrict__ edge0, const float* __restrict__ bias,
                                                     float* __restrict__ outf,
                                                     const float* __restrict__ fcw, const float* __restrict__ fcb,
                                                     float* __restrict__ out6) {
    const int lane = threadIdx.x & 63;
    const int bid = blockIdx.x;
    const int d = (bid & 7) * N_NODES + (bid >> 3) * 4 + (threadIdx.x >> 6);
    const int e0 = offs[d], e1 = offs[d + 1];
    const fx4 ad4 = *(const fx4*)&AD[d * 4];
    float den0 = 0.f, den1 = 0.f, den2 = 0.f, den3 = 0.f;
    float acc[8] = {0.f, 0.f, 0.f, 0.f, 0.f, 0.f, 0.f, 0.f};
    for (int e = e0; e < e1; ++e) {
        const int src = decode_src(esort[e], edge0);
        const fx4 as4 = *(const fx4*)&AS[src * 4];
        float v0 = as4.x + ad4.x; v0 = v0 > 0.f ? v0 : 0.2f * v0;
        float v1 = as4.y + ad4.y; v1 = v1 > 0.f ? v1 : 0.2f * v1;
        float v2 = as4.z + ad4.z; v2 = v2 > 0.f ? v2 : 0.2f * v2;
        float v3 = as4.w + ad4.w; v3 = v3 > 0.f ? v3 : 0.2f * v3;
        const float ex0 = __expf(v0), ex1 = __expf(v1), ex2 = __expf(v2), ex3 = __expf(v3);
        den0 += ex0; den1 += ex1; den2 += ex2; den3 += ex3;
        const unsigned int* wr = (const unsigned int*)(whb + (size_t)src * 512);
        const unsigned int u0 = wr[lane];
        const unsigned int u1 = wr[64 + lane];
        const unsigned int u2 = wr[128 + lane];
        const unsigned int u3 = wr[192 + lane];
        acc[0] += ex0 * bfu((unsigned short)u0);
        acc[1] += ex0 * bfu((unsigned short)(u0 >> 16));
        acc[2] += ex1 * bfu((unsigned short)u1);
        acc[3] += ex1 * bfu((unsigned short)(u1 >> 16));
        acc[4] += ex2 * bfu((unsigned short)u2);
        acc[5] += ex2 * bfu((unsigned short)(u2 >> 16));
        acc[6] += ex3 * bfu((unsigned short)u3);
        acc[7] += ex3 * bfu((unsigned short)(u3 >> 16));
    }
    const float i0v = rcpf_(den0 + 1e-16f), i1v = rcpf_(den1 + 1e-16f);
    const float i2v = rcpf_(den2 + 1e-16f), i3v = rcpf_(den3 + 1e-16f);
    const int c0i = 2 * lane, c1i = 2 * lane + 1;
    const float o0r = 0.25f * (acc[0] * i0v + acc[2] * i1v + acc[4] * i2v + acc[6] * i3v) + bias[c0i];
    const float o1r = 0.25f * (acc[1] * i0v + acc[3] * i1v + acc[5] * i2v + acc[7] * i3v) + bias[c1i];
    const float o0 = fmaxf(o0r, 0.f);
    const float o1 = fmaxf(o1r, 0.f);
    if (fcw == nullptr) {
        fx2 ov = { o0, o1 };
        *(fx2*)&outf[(size_t)d * 128 + c0i] = ov;
    } else {
        float p[6];
#pragma unroll
        for (int m = 0; m < 6; ++m) p[m] = o0 * fcw[m * 128 + c0i] + o1 * fcw[m * 128 + c1i];
#pragma unroll
        for (int off = 32; off > 0; off >>= 1) {
#pragma unroll
            for (int m = 0; m < 6; ++m) p[m] += __shfl_down(p[m], off);
        }
        if (lane == 0) {
#pragma unroll
            for (int m = 0; m < 6; ++m) out6[(size_t)d * 6 + m] = p[m] + fcb[m];
        }
    }
}

extern "C" void kernel_launch(void* const* d_in, const int* in_sizes, int n_in,
                              void* d_out, int out_size, void* d_ws, size_t ws_size,
                              hipStream_t stream) {
    const float* x = (const float*)d_in[0];
    const float* wih0 = (const float*)d_in[1];
    const float* whh0 = (const float*)d_in[2];
    const float* bih0 = (const float*)d_in[3];
    const float* bhh0 = (const float*)d_in[4];
    const float* wih1 = (const float*)d_in[5];
    const float* whh1 = (const float*)d_in[6];
    const float* bih1 = (const float*)d_in[7];
    const float* bhh1 = (const float*)d_in[8];
    const float* g1w = (const float*)d_in[9];
    const float* g1as = (const float*)d_in[10];
    const float* g1ad = (const float*)d_in[11];
    const float* g1b = (const float*)d_in[12];
    const float* g2w = (const float*)d_in[13];
    const float* g2as = (const float*)d_in[14];
    const float* g2ad = (const float*)d_in[15];
    const float* g2b = (const float*)d_in[16];
    const float* fcw = (const float*)d_in[17];
    const float* fcb = (const float*)d_in[18];
    const int* eidx = (const int*)d_in[19];
    const int* edge0 = eidx;
    const int* edge1 = eidx + E_EDGES;

    char* ws = (char*)d_ws;
    float* H0 = (float*)ws;                               // 40000*128 f32
    float* H1 = (float*)(ws + 20480000);                  // 40000*128 f32
    unsigned short* WHB = (unsigned short*)(ws + 40960000); // 40000*512 bf16
    float* AS = (float*)(ws + 122880000);                 // 40000*4 f32
    float* AD = (float*)(ws + 123520000);                 // 40000*4 f32
    short* PK = (short*)(ws + 124160000);                 // 290816 bf16 packed weights
    int* OFFS = (int*)(ws + 124765184);                   // 40001 int
    int* CURS = (int*)(ws + 124925248);                   // 40000 int (also cnt)
    int* ESORT = (int*)(ws + 125085248);                  // 680000 int

    hipMemsetAsync(CURS, 0, BN_TOTAL * sizeof(int), stream);
    pack_w<<<1136, 256, 0, stream>>>(wih0, whh0, wih1, whh1, g1w, g2w, PK);
    csr_count<<<(NE + 255) / 256, 256, 0, stream>>>(edge1, CURS);
    csr_scan<<<1, 1024, 0, stream>>>(CURS, OFFS, CURS);
    csr_fill<<<(NE + 255) / 256, 256, 0, stream>>>(edge1, CURS, ESORT);

    gru_mfma<<<1250, 512, 0, stream>>>(x, PK, bih0, bhh0, bih1, bhh1, H0);

    dim3 gg(313, 4);
    gat_gemm<<<gg, 256, 0, stream>>>(H0, PK + 159744, g1as, g1ad, WHB, AS, AD);
    gat_aggregate<<<10000, 256, 0, stream>>>(WHB, AS, AD, OFFS, ESORT, edge0, g1b, H1,
                                             nullptr, nullptr, nullptr);

    gat_gemm<<<gg, 256, 0, stream>>>(H1, PK + 225280, g2as, g2ad, WHB, AS, AD);
    gat_aggregate<<<10000, 256, 0, stream>>>(WHB, AS, AD, OFFS, ESORT, edge0, g2b, nullptr,
                                             fcw, fcb, (float*)d_out);
}